// Round 2
// baseline (1312.761 us; speedup 1.0000x reference)
//
#include <hip/hip_runtime.h>
#include <stdint.h>

// ---------------- problem constants ----------------
#define K_H    8
#define K_D    64
#define K_G    64
#define K_DIM  256
#define K_INNER 512
#define K_B    4
#define K_N    32768

// ---------------- LDS layout ----------------
#define XS          264                   // x tile row stride (bf16 elems), 528B, 16B aligned
#define XLDS_BYTES  (64 * XS * 2)         // 33792
#define BUFA_STR    72                    // fx^T rows, 144B, 16B aligned
#define BUFA_BYTES  (64 * BUFA_STR * 2)   // 9216
#define BUF2_STR    40                    // sw^T rows, 80B, 16B aligned
#define BUF2_BYTES  (64 * BUF2_STR * 2)   // 5120
#define P1_WAVE_BYTES (BUFA_BYTES + BUF2_BYTES)         // 14336
#define P1_LDS      (XLDS_BYTES + 8 * P1_WAVE_BYTES)    // 148480  (<=160K)
#define SW_STR      520                   // sw[n][512] rows, 1040B, 16B aligned
#define SW_BYTES    (64 * SW_STR * 2)     // 66560
#define P3_LDS      (XLDS_BYTES + SW_BYTES)             // 100352
#define P2_LDS      (5 * 64 * 65 * 4 + 2 * 64 * 4)      // 83712

// ---------------- workspace layout (bytes) ----------------
#define WFX_OFF   0                        // 512*256 bf16       = 262144
#define WEFF_OFF  262144                   // 8*64*256 bf16      = 262144
#define BEFF_OFF  524288                   // 512 f32            = 2048
#define STF_OFF   526336                   // 4*8*4096 f32       = 524288
#define MT_OFF    1050624                  // 4*256*512 bf16     = 1048576
#define PARTS_OFF 2099200                  // 4*bpb*8*4096 f32 (+ partn after)

typedef __attribute__((ext_vector_type(8))) short short8;  // 8 x bf16 (4 VGPRs)
typedef __attribute__((ext_vector_type(4))) float f4;      // MFMA C/D frag
typedef __attribute__((ext_vector_type(4))) unsigned short us4;

static __device__ __forceinline__ f4 MFMA(short8 a, short8 b, f4 c) {
  return __builtin_amdgcn_mfma_f32_16x16x32_bf16(a, b, c, 0, 0, 0);
}
static __device__ __forceinline__ unsigned short f2bf(float f) {
  union { float f; unsigned u; } v; v.f = f;
  unsigned r = v.u + 0x7FFFu + ((v.u >> 16) & 1u);  // RNE
  return (unsigned short)(r >> 16);
}
static __device__ __forceinline__ us4 pack4(f4 v) {
  us4 p; p[0] = f2bf(v[0]); p[1] = f2bf(v[1]); p[2] = f2bf(v[2]); p[3] = f2bf(v[3]);
  return p;
}
// stage one 64x256 fp32 tile -> bf16 LDS [64][XS]
static __device__ __forceinline__ void stage_x(const float* __restrict__ xp,
                                               unsigned short* xlds, int tid) {
#pragma unroll
  for (int j = 0; j < 8; ++j) {
    int fi = j * 2048 + tid * 4;
    float4 v = *(const float4*)(xp + fi);
    int row = fi >> 8, col = fi & 255;
    us4 p; p[0] = f2bf(v.x); p[1] = f2bf(v.y); p[2] = f2bf(v.z); p[3] = f2bf(v.w);
    *(us4*)(xlds + row * XS + col) = p;
  }
}

// ---------------- prep: Wfx -> bf16 ----------------
__global__ void prep_conv(const float* __restrict__ Wfx, unsigned short* __restrict__ wfxb) {
  int i = blockIdx.x * 256 + threadIdx.x;   // grid 512*256 = 131072 exact
  wfxb[i] = f2bf(Wfx[i]);
}

// ---------------- prep: Weff = (Wslice @ Wx_h) * inv_t, beff = (Wslice@bx + bsl)*inv_t ----
__global__ void prep_weff(const float* __restrict__ Wx, const float* __restrict__ Wsl,
                          const float* __restrict__ bx, const float* __restrict__ bsl,
                          const float* __restrict__ temp,
                          unsigned short* __restrict__ weff, float* __restrict__ beff) {
  int hg = blockIdx.x;        // 0..511
  int h = hg >> 6, g = hg & 63;
  int k = threadIdx.x;        // 0..255
  float inv_t = 1.0f / temp[h];
  float acc = 0.f;
  for (int d = 0; d < 64; ++d)
    acc += Wsl[g * 64 + d] * Wx[(size_t)(h * 64 + d) * 256 + k];
  weff[(size_t)hg * 256 + k] = f2bf(acc * inv_t);
  if (k == 0) {
    float bb = bsl[g];
    for (int d = 0; d < 64; ++d) bb += Wsl[g * 64 + d] * bx[h * 64 + d];
    beff[hg] = bb * inv_t;
  }
}

// ---------------- pass1: logits(Weff) + softmax + fx + pool -> partial writes ----------------
__launch_bounds__(512, 2)
__global__ void pass1_kernel(const float* __restrict__ x,
                             const unsigned short* __restrict__ wfx,
                             const unsigned short* __restrict__ weff,
                             const float* __restrict__ beff,
                             const float* __restrict__ bfx,
                             float* __restrict__ parts,
                             float* __restrict__ partn,
                             int tpb) {
  extern __shared__ char lds[];
  const int tid = threadIdx.x;
  const int lane = tid & 63;
  const int h = tid >> 6;          // wave id == head
  const int l15 = lane & 15;
  const int q = lane >> 4;
  const int bpb = gridDim.x >> 2;
  const int b = blockIdx.x / bpb;
  const int blb = blockIdx.x - b * bpb;

  unsigned short* xlds = (unsigned short*)lds;
  unsigned short* bufA = (unsigned short*)(lds + XLDS_BYTES + h * P1_WAVE_BYTES);
  unsigned short* buf2 = bufA + BUFA_BYTES / 2;

  float bfx_v[4];
#pragma unroll
  for (int ci = 0; ci < 4; ++ci) bfx_v[ci] = bfx[h * 64 + 16 * ci + l15];
  f4 bot[4];
#pragma unroll
  for (int gi = 0; gi < 4; ++gi)
#pragma unroll
    for (int r = 0; r < 4; ++r) bot[gi][r] = beff[h * 64 + 16 * gi + 4 * q + r];

  const f4 fz = {0.f, 0.f, 0.f, 0.f};
  f4 stacc[4][4];   // st[g][c] accumulator, persistent over tiles
  f4 snacc[4];      // snorm partial per lane
#pragma unroll
  for (int i = 0; i < 4; ++i) {
    snacc[i] = fz;
#pragma unroll
    for (int j = 0; j < 4; ++j) stacc[i][j] = fz;
  }

  for (int t = 0; t < tpb; ++t) {
    const int n0 = (blb * tpb + t) * 64;
    const float* xp = x + ((size_t)b * K_N + n0) * K_DIM;
    __syncthreads();
    stage_x(xp, xlds, tid);
    __syncthreads();

    // ---- logits^T GEMM: D[g][n] = sum_k Weff[g][k] * x[n][k]  (K=256) ----
    f4 accL[4][4];
#pragma unroll
    for (int i = 0; i < 4; ++i)
#pragma unroll
      for (int j = 0; j < 4; ++j) accL[i][j] = fz;
#pragma unroll
    for (int ks = 0; ks < 8; ++ks) {
      short8 xb[4], wa[4];
#pragma unroll
      for (int ni = 0; ni < 4; ++ni)
        xb[ni] = *(const short8*)(xlds + (16 * ni + l15) * XS + 32 * ks + 8 * q);
#pragma unroll
      for (int gi = 0; gi < 4; ++gi)
        wa[gi] = *(const short8*)(weff + (size_t)(h * 64 + 16 * gi + l15) * K_DIM + 32 * ks + 8 * q);
#pragma unroll
      for (int gi = 0; gi < 4; ++gi)
#pragma unroll
        for (int ni = 0; ni < 4; ++ni)
          accL[gi][ni] = MFMA(wa[gi], xb[ni], accL[gi][ni]);
    }
#pragma unroll
    for (int gi = 0; gi < 4; ++gi)
#pragma unroll
      for (int ni = 0; ni < 4; ++ni)
        accL[gi][ni] = accL[gi][ni] + bot[gi];

    // ---- softmax over g: in-lane 16 regs + shuffle over quads ----
    unsigned swp[4][4][2];
#pragma unroll
    for (int ni = 0; ni < 4; ++ni) {
      float m = -3.0e38f;
#pragma unroll
      for (int gi = 0; gi < 4; ++gi)
#pragma unroll
        for (int r = 0; r < 4; ++r) m = fmaxf(m, accL[gi][ni][r]);
      m = fmaxf(m, __shfl_xor(m, 16));
      m = fmaxf(m, __shfl_xor(m, 32));
      float s = 0.f;
#pragma unroll
      for (int gi = 0; gi < 4; ++gi) {
        f4 e;
#pragma unroll
        for (int r = 0; r < 4; ++r) e[r] = __expf(accL[gi][ni][r] - m);
        accL[gi][ni] = e;
        s += e[0] + e[1] + e[2] + e[3];
      }
      s += __shfl_xor(s, 16);
      s += __shfl_xor(s, 32);
      const float rinv = 1.0f / s;
#pragma unroll
      for (int gi = 0; gi < 4; ++gi) {
        accL[gi][ni] *= rinv;
        snacc[gi] += accL[gi][ni];
        swp[gi][ni][0] = (unsigned)f2bf(accL[gi][ni][0]) | ((unsigned)f2bf(accL[gi][ni][1]) << 16);
        swp[gi][ni][1] = (unsigned)f2bf(accL[gi][ni][2]) | ((unsigned)f2bf(accL[gi][ni][3]) << 16);
      }
    }

    // ---- fx GEMM: D[n][c] = sum_k x[n][k] * Wfx[c][k] ----
    f4 accF[4][4];
#pragma unroll
    for (int i = 0; i < 4; ++i)
#pragma unroll
      for (int j = 0; j < 4; ++j) accF[i][j] = fz;
#pragma unroll
    for (int ks = 0; ks < 8; ++ks) {
      short8 xa[4], wb[4];
#pragma unroll
      for (int mi = 0; mi < 4; ++mi)
        xa[mi] = *(const short8*)(xlds + (16 * mi + l15) * XS + 32 * ks + 8 * q);
#pragma unroll
      for (int ci = 0; ci < 4; ++ci)
        wb[ci] = *(const short8*)(wfx + (size_t)(h * 64 + 16 * ci + l15) * K_DIM + 32 * ks + 8 * q);
#pragma unroll
      for (int mi = 0; mi < 4; ++mi)
#pragma unroll
        for (int ci = 0; ci < 4; ++ci)
          accF[mi][ci] = MFMA(xa[mi], wb[ci], accF[mi][ci]);
    }
    // flush fx^T[c][n] (fast quad writes along n)
#pragma unroll
    for (int mi = 0; mi < 4; ++mi)
#pragma unroll
      for (int ci = 0; ci < 4; ++ci) {
        f4 v = accF[mi][ci] + bfx_v[ci];
        *(us4*)(bufA + (16 * ci + l15) * BUFA_STR + 16 * mi + 4 * q) = pack4(v);
      }

    // ---- pooling: st[g][c] += sum_n sw[n][g] * fx[n][c] ----
#pragma unroll
    for (int kh = 0; kh < 2; ++kh) {
#pragma unroll
      for (int gi = 0; gi < 4; ++gi)
#pragma unroll
        for (int nn = 0; nn < 2; ++nn) {
          const int ni = 2 * kh + nn;
#pragma unroll
          for (int r = 0; r < 4; ++r) {
            unsigned wv = swp[gi][ni][r >> 1];
            buf2[(16 * gi + 4 * q + r) * BUF2_STR + 16 * nn + l15] =
                (unsigned short)(wv >> (16 * (r & 1)));
          }
        }
      short8 aw[4], bw[4];
#pragma unroll
      for (int mt = 0; mt < 4; ++mt)
        aw[mt] = *(const short8*)(buf2 + (16 * mt + l15) * BUF2_STR + 8 * q);
#pragma unroll
      for (int ct = 0; ct < 4; ++ct)
        bw[ct] = *(const short8*)(bufA + (16 * ct + l15) * BUFA_STR + 32 * kh + 8 * q);
#pragma unroll
      for (int mt = 0; mt < 4; ++mt)
#pragma unroll
        for (int ct = 0; ct < 4; ++ct)
          stacc[mt][ct] = MFMA(aw[mt], bw[ct], stacc[mt][ct]);
    }
  }

  // ---- flush per-block partials (plain coalesced stores, NO atomics) ----
  float* stp = parts + (((size_t)(b * bpb + blb)) * 8 + h) * 4096;
#pragma unroll
  for (int gi = 0; gi < 4; ++gi)
#pragma unroll
    for (int ci = 0; ci < 4; ++ci)
#pragma unroll
      for (int r = 0; r < 4; ++r)
        stp[(16 * gi + 4 * q + r) * 64 + 16 * ci + l15] = stacc[gi][ci][r];
  float* snp = partn + ((size_t)(b * bpb + blb)) * 512 + h * 64;
#pragma unroll
  for (int gi = 0; gi < 4; ++gi)
#pragma unroll
    for (int r = 0; r < 4; ++r) {
      float vv = snacc[gi][r];
      vv += __shfl_xor(vv, 1);
      vv += __shfl_xor(vv, 2);
      vv += __shfl_xor(vv, 4);
      vv += __shfl_xor(vv, 8);
      if (l15 == 0) snp[16 * gi + 4 * q + r] = vv;
    }
}

// ---------------- reduce: sum partials, divide by snorm ----------------
__global__ void reduce_kernel(const float* __restrict__ parts, const float* __restrict__ partn,
                              float* __restrict__ stf, int bpb) {
  // grid 128: block = b*32 + h*4 + c4
  const int blk = blockIdx.x;
  const int b = blk >> 5, h = (blk >> 2) & 7, c4 = blk & 3;
  const int tid = threadIdx.x;
  __shared__ float snl[16];
  if (tid < 16) {
    int g = c4 * 16 + tid;
    float s = 0.f;
    for (int p = 0; p < bpb; ++p)
      s += partn[((size_t)(b * bpb + p)) * 512 + h * 64 + g];
    snl[tid] = 1.0f / (s + 1e-5f);
  }
  __syncthreads();
  const int base = c4 * 1024;
#pragma unroll
  for (int k = 0; k < 4; ++k) {
    int i = base + k * 256 + tid;
    float s = 0.f;
    for (int p = 0; p < bpb; ++p)
      s += parts[(((size_t)(b * bpb + p)) * 8 + h) * 4096 + i];
    stf[((size_t)(b * 8 + h)) * 4096 + i] = s * snl[(i >> 6) - c4 * 16];
  }
}

// ---------------- pass2: slice-token attention + Mt = out_st @ Wout_h^T ----------------
__global__ void pass2_kernel(const float* __restrict__ stf,
                             const float* __restrict__ Wq, const float* __restrict__ Wk,
                             const float* __restrict__ Wv, const float* __restrict__ attn_scale,
                             const float* __restrict__ res_scale,
                             const float* __restrict__ Wout,
                             unsigned short* __restrict__ mt) {
  extern __shared__ char lds2[];
  float* st = (float*)lds2;        // [64][65]
  float* kv = st + 64 * 65;        // reused as attn later
  float* kk = kv + 64 * 65;
  float* vv = kk + 64 * 65;
  float* qq = vv + 64 * 65;        // reused as out_st later
  float* nk = qq + 64 * 65;        // [64]
  float* nq = nk + 64;             // [64]
  const int b = blockIdx.x >> 3, h = blockIdx.x & 7;
  const int tid = threadIdx.x;

#pragma unroll
  for (int j = 0; j < 16; ++j) {
    int idx = tid + 256 * j;
    int g = idx >> 6, d = idx & 63;
    float sv = stf[((size_t)(b * 8 + h)) * 4096 + idx];
    float kvv = 0.f;
    for (int h2 = 0; h2 < 8; ++h2)
      kvv += stf[((size_t)(b * 8 + h2)) * 4096 + idx];
    st[g * 65 + d] = sv;
    kv[g * 65 + d] = kvv * 0.125f;
  }
  __syncthreads();
#pragma unroll 2
  for (int j = 0; j < 16; ++j) {
    int idx = tid + 256 * j;
    int g = idx >> 6, dp = idx & 63;
    float a1 = 0, a2 = 0, a3 = 0;
    for (int dd = 0; dd < 64; ++dd) {
      float kvv = kv[g * 65 + dd], stv = st[g * 65 + dd];
      a1 += kvv * Wk[dp * 64 + dd];
      a2 += kvv * Wv[dp * 64 + dd];
      a3 += stv * Wq[dp * 64 + dd];
    }
    kk[g * 65 + dp] = a1;
    vv[g * 65 + dp] = a2;
    qq[g * 65 + dp] = a3;
  }
  __syncthreads();
  if (tid < 128) {
    int g = tid & 63;
    const float* p = (tid >= 64) ? qq : kk;
    float s = 0;
    for (int d = 0; d < 64; ++d) { float v = p[g * 65 + d]; s += v * v; }
    float nrm = fmaxf(sqrtf(s), 1e-12f);
    ((tid >= 64) ? nq : nk)[g] = nrm;
  }
  __syncthreads();
  const float scale = attn_scale[h];
  float* at = kv;  // reuse
#pragma unroll 2
  for (int j = 0; j < 16; ++j) {
    int idx = tid + 256 * j;
    int g = idx >> 6, s2 = idx & 63;
    float a = 0;
    for (int d = 0; d < 64; ++d) a += qq[g * 65 + d] * kk[s2 * 65 + d];
    at[g * 65 + s2] = a * scale / (nq[g] * nk[s2]);
  }
  __syncthreads();
  if (tid < 64) {
    int g = tid;
    float m = -3.0e38f;
    for (int s2 = 0; s2 < 64; ++s2) m = fmaxf(m, at[g * 65 + s2]);
    float ssum = 0;
    for (int s2 = 0; s2 < 64; ++s2) {
      float e = __expf(at[g * 65 + s2] - m);
      at[g * 65 + s2] = e;
      ssum += e;
    }
    float r = 1.f / ssum;
    for (int s2 = 0; s2 < 64; ++s2) at[g * 65 + s2] *= r;
  }
  __syncthreads();
  const float rs = res_scale[0];
  float ost_r[16];
#pragma unroll 2
  for (int j = 0; j < 16; ++j) {
    int idx = tid + 256 * j;
    int g = idx >> 6, d = idx & 63;
    float o = 0;
    for (int s2 = 0; s2 < 64; ++s2) o += at[g * 65 + s2] * vv[s2 * 65 + d];
    ost_r[j] = o + rs * st[g * 65 + d];
  }
  __syncthreads();   // qq reads (attn) all done
#pragma unroll
  for (int j = 0; j < 16; ++j) {
    int idx = tid + 256 * j;
    int g = idx >> 6, d = idx & 63;
    qq[g * 65 + d] = ost_r[j];   // out_st -> qq slot
  }
  __syncthreads();
  // Mt[b][cout][h*64+g] = sum_d out_st[g][d] * Wout[cout][h*64+d]
  {
    const int cout = tid;  // 256 threads = 256 cout
    float w[64];
#pragma unroll
    for (int d = 0; d < 64; ++d) w[d] = Wout[(size_t)cout * 512 + h * 64 + d];
    for (int g = 0; g < 64; ++g) {
      float acc = 0.f;
#pragma unroll
      for (int d = 0; d < 64; ++d) acc += qq[g * 65 + d] * w[d];
      mt[((size_t)b * 256 + cout) * 512 + h * 64 + g] = f2bf(acc);
    }
  }
}

// ---------------- pass3: logits + softmax + single K=512 GEMM (Mt) ----------------
__launch_bounds__(512, 2)
__global__ void pass3_kernel(const float* __restrict__ x,
                             const unsigned short* __restrict__ weff,
                             const float* __restrict__ beff,
                             const unsigned short* __restrict__ mt,
                             const float* __restrict__ bout,
                             float* __restrict__ out) {
  extern __shared__ char lds[];
  const int tid = threadIdx.x;
  const int lane = tid & 63;
  const int h = tid >> 6;
  const int l15 = lane & 15;
  const int q = lane >> 4;
  const int b = blockIdx.x >> 9;          // 512 blocks per batch
  const int n0 = (blockIdx.x & 511) * 64;

  unsigned short* xlds = (unsigned short*)lds;
  unsigned short* swb = (unsigned short*)(lds + XLDS_BYTES);  // [64 n][SW_STR]

  f4 bot[4];
#pragma unroll
  for (int gi = 0; gi < 4; ++gi)
#pragma unroll
    for (int r = 0; r < 4; ++r) bot[gi][r] = beff[h * 64 + 16 * gi + 4 * q + r];
  float bout_v[2];
#pragma unroll
  for (int nt = 0; nt < 2; ++nt) bout_v[nt] = bout[32 * h + 16 * nt + l15];

  const float* xp = x + ((size_t)b * K_N + n0) * K_DIM;
  stage_x(xp, xlds, tid);
  __syncthreads();

  const f4 fz = {0.f, 0.f, 0.f, 0.f};
  // ---- logits^T GEMM (K=256, Weff) ----
  f4 accL[4][4];
#pragma unroll
  for (int i = 0; i < 4; ++i)
#pragma unroll
    for (int j = 0; j < 4; ++j) accL[i][j] = fz;
#pragma unroll
  for (int ks = 0; ks < 8; ++ks) {
    short8 xb[4], wa[4];
#pragma unroll
    for (int ni = 0; ni < 4; ++ni)
      xb[ni] = *(const short8*)(xlds + (16 * ni + l15) * XS + 32 * ks + 8 * q);
#pragma unroll
    for (int gi = 0; gi < 4; ++gi)
      wa[gi] = *(const short8*)(weff + (size_t)(h * 64 + 16 * gi + l15) * K_DIM + 32 * ks + 8 * q);
#pragma unroll
    for (int gi = 0; gi < 4; ++gi)
#pragma unroll
      for (int ni = 0; ni < 4; ++ni)
        accL[gi][ni] = MFMA(wa[gi], xb[ni], accL[gi][ni]);
  }
#pragma unroll
  for (int gi = 0; gi < 4; ++gi)
#pragma unroll
    for (int ni = 0; ni < 4; ++ni)
      accL[gi][ni] = accL[gi][ni] + bot[gi];
  // ---- softmax over g ----
#pragma unroll
  for (int ni = 0; ni < 4; ++ni) {
    float m = -3.0e38f;
#pragma unroll
    for (int gi = 0; gi < 4; ++gi)
#pragma unroll
      for (int r = 0; r < 4; ++r) m = fmaxf(m, accL[gi][ni][r]);
    m = fmaxf(m, __shfl_xor(m, 16));
    m = fmaxf(m, __shfl_xor(m, 32));
    float s = 0.f;
#pragma unroll
    for (int gi = 0; gi < 4; ++gi) {
      f4 e;
#pragma unroll
      for (int r = 0; r < 4; ++r) e[r] = __expf(accL[gi][ni][r] - m);
      accL[gi][ni] = e;
      s += e[0] + e[1] + e[2] + e[3];
    }
    s += __shfl_xor(s, 16);
    s += __shfl_xor(s, 32);
    const float rinv = 1.0f / s;
#pragma unroll
    for (int gi = 0; gi < 4; ++gi) accL[gi][ni] *= rinv;
  }
  // ---- stage sw[n][h*64+g] (fast quad us4 writes; each wave fills its head's 64 cols) ----
#pragma unroll
  for (int gi = 0; gi < 4; ++gi)
#pragma unroll
    for (int ni = 0; ni < 4; ++ni)
      *(us4*)(swb + (16 * ni + l15) * SW_STR + h * 64 + 16 * gi + 4 * q) = pack4(accL[gi][ni]);
  __syncthreads();

  // ---- final GEMM: out[n][cout] = sum_{hg} sw[n][hg] * Mt[cout][hg] + bout ----
  f4 accC[4][2];
#pragma unroll
  for (int i = 0; i < 4; ++i)
#pragma unroll
    for (int j = 0; j < 2; ++j) accC[i][j] = fz;
#pragma unroll
  for (int ks = 0; ks < 16; ++ks) {
    short8 ax[4], bm[2];
#pragma unroll
    for (int mt2 = 0; mt2 < 4; ++mt2)
      ax[mt2] = *(const short8*)(swb + (16 * mt2 + l15) * SW_STR + 32 * ks + 8 * q);
#pragma unroll
    for (int nt = 0; nt < 2; ++nt)
      bm[nt] = *(const short8*)(mt + ((size_t)b * 256 + 32 * h + 16 * nt + l15) * 512 + 32 * ks + 8 * q);
#pragma unroll
    for (int mt2 = 0; mt2 < 4; ++mt2)
#pragma unroll
      for (int nt = 0; nt < 2; ++nt)
        accC[mt2][nt] = MFMA(ax[mt2], bm[nt], accC[mt2][nt]);
  }
  float* op2 = out + ((size_t)b * K_N + n0) * K_DIM;
#pragma unroll
  for (int mt2 = 0; mt2 < 4; ++mt2)
#pragma unroll
    for (int nt = 0; nt < 2; ++nt) {
      f4 v = accC[mt2][nt] + bout_v[nt];
#pragma unroll
      for (int r = 0; r < 4; ++r)
        op2[(size_t)(16 * mt2 + 4 * q + r) * K_DIM + 32 * h + 16 * nt + l15] = v[r];
    }
}

// ---------------- host launch ----------------
extern "C" void kernel_launch(void* const* d_in, const int* in_sizes, int n_in,
                              void* d_out, int out_size, void* d_ws, size_t ws_size,
                              hipStream_t stream) {
  const float* x    = (const float*)d_in[0];
  const float* Wfx  = (const float*)d_in[1];
  const float* bfx  = (const float*)d_in[2];
  const float* Wx   = (const float*)d_in[3];
  const float* bx   = (const float*)d_in[4];
  const float* Wsl  = (const float*)d_in[5];
  const float* bsl  = (const float*)d_in[6];
  const float* temp = (const float*)d_in[7];
  const float* Wq   = (const float*)d_in[8];
  const float* Wk   = (const float*)d_in[9];
  const float* Wv   = (const float*)d_in[10];
  const float* rs   = (const float*)d_in[11];
  const float* asc  = (const float*)d_in[12];
  const float* Wout = (const float*)d_in[13];
  const float* bout = (const float*)d_in[14];
  float* out = (float*)d_out;
  char* ws = (char*)d_ws;

  // adaptive partial-buffer sizing (ws_size fixed across calls -> deterministic)
  int bpb = 64;
  while (bpb > 8) {
    size_t need = (size_t)PARTS_OFF + (size_t)4 * bpb * (8 * 4096 + 512) * 4;
    if (need <= ws_size) break;
    bpb >>= 1;
  }
  const int tpb = 512 / bpb;

  unsigned short* wfxb = (unsigned short*)(ws + WFX_OFF);
  unsigned short* weff = (unsigned short*)(ws + WEFF_OFF);
  float* beff = (float*)(ws + BEFF_OFF);
  float* stf  = (float*)(ws + STF_OFF);
  unsigned short* mtp = (unsigned short*)(ws + MT_OFF);
  float* parts = (float*)(ws + PARTS_OFF);
  float* partn = (float*)(ws + PARTS_OFF + (size_t)4 * bpb * 8 * 4096 * 4);

  (void)hipFuncSetAttribute((const void*)pass1_kernel,
                            hipFuncAttributeMaxDynamicSharedMemorySize, P1_LDS);
  (void)hipFuncSetAttribute((const void*)pass2_kernel,
                            hipFuncAttributeMaxDynamicSharedMemorySize, P2_LDS);
  (void)hipFuncSetAttribute((const void*)pass3_kernel,
                            hipFuncAttributeMaxDynamicSharedMemorySize, P3_LDS);

  prep_conv<<<512, 256, 0, stream>>>(Wfx, wfxb);
  prep_weff<<<512, 256, 0, stream>>>(Wx, Wsl, bx, bsl, temp, weff, beff);
  pass1_kernel<<<4 * bpb, 512, P1_LDS, stream>>>(x, wfxb, weff, beff, bfx, parts, partn, tpb);
  reduce_kernel<<<128, 256, 0, stream>>>(parts, partn, stf, bpb);
  pass2_kernel<<<32, 256, P2_LDS, stream>>>(stf, Wq, Wk, Wv, asc, rs, Wout, mtp);
  pass3_kernel<<<2048, 512, P3_LDS, stream>>>(x, weff, beff, mtp, bout, out);
}